// Round 3
// baseline (127.862 us; speedup 1.0000x reference)
//
#include <hip/hip_runtime.h>
#include <hip/hip_bf16.h>

// SimpleRetention: B=8, SEQ=2048, HIDDEN=512, HEAD=64, CHUNK=256, GAMMA=0.96875
// v3: fragment-layout everywhere; attn is barrier-free in the hot loop.
//   prep: W -> B-frag layout (Wfrag), xpos tables
//   proj: X@W via MFMA (only X staged in LDS, 14 KB), epilogue emits
//         Qfrag (A-layout), Kfrag, Vfrag (B-layouts) via LDS transpose
//   attn: 512 blocks = (b, 32 q-rows); 4 waves = (q-half, chunk-half);
//         wave-private P round-trip, no __syncthreads in the chunk loop.

typedef __attribute__((ext_vector_type(8))) short short8;
typedef __attribute__((ext_vector_type(4))) float floatx4;

#define LOG2GAMMA (-0.04580350f)  // log2(0.96875)

static __device__ __forceinline__ unsigned short f2bf(float f) {
    __hip_bfloat16 h = __float2bfloat16(f);
    return *reinterpret_cast<unsigned short*>(&h);
}

// Fragment storage convention (per 16x16x32 MFMA load, 16 B per lane):
//   frag_slot = ((tile_k_index)*64 + lane)*8,  lane = quad*16 + l15
//   A-frag: l15 = row m, k = quad*8+j   |   B-frag: l15 = col n, k = quad*8+j

// ---------------------------------------------------------------------------
// Kernel 0: Wfrag (B-frag order, tiles 0..3=WQ 4..7=WK 8..11=WV) + xpos tables
// tabs: 4 tables of [2048][32] f32: 0=cosQ 1=sinQ 2=cosK 3=sinK
// ---------------------------------------------------------------------------
__global__ __launch_bounds__(256) void prep_kernel(
    const float* __restrict__ Wq, const float* __restrict__ Wk,
    const float* __restrict__ Wv,
    __hip_bfloat16* __restrict__ Wfrag, float* __restrict__ tabs)
{
    int idx = blockIdx.x * 256 + threadIdx.x;
    const int WF_N = 192 * 512;
    if (idx < WF_N) {
        // decode frag offset: ((tile*16 + kkg)*64 + quad*16 + n15)*8 + j
        int j    = idx & 7;
        int n15  = (idx >> 3) & 15;
        int quad = (idx >> 7) & 3;
        int kkg  = (idx >> 9) & 15;
        int tile = idx >> 13;              // 0..11
        int n = tile * 16 + n15;           // 0..191 (proj output channel)
        int k = kkg * 32 + quad * 8 + j;   // 0..511 (hidden)
        int m = n >> 6, c = n & 63;
        const float* W = (m == 0) ? Wq : ((m == 1) ? Wk : Wv);
        Wfrag[idx] = __float2bfloat16(W[k * 64 + c]);
    } else {
        int t2 = idx - WF_N;
        if (t2 < 4 * 2048 * 32) {
            int tab = t2 >> 16;          // 0..3
            int rem = t2 & 65535;
            int pos = rem >> 5;          // 0..2047
            int t   = rem & 31;          // 0..31
            float inv_freq = powf(10000.0f, -(float)t / 32.0f);
            float sinus = (float)pos * inv_freq;
            float s = sinf(sinus), c = cosf(sinus);
            float sv = (2.0f * (float)t + 0.4f * 64.0f) / (1.4f * 64.0f);
            float power = (float)pos / 512.0f;
            float scl = powf(sv, (tab >= 2) ? -power : power);
            tabs[t2] = ((tab & 1) == 0) ? c * scl : s * scl;
        }
    }
}

// ---------------------------------------------------------------------------
// Kernel 1: projections. 512 blocks x 32 rows, 4 waves (rh, nh).
// Only X staged in LDS (8.5 KB); W B-frags load coalesced from L2 Wfrag.
// Epilogue: xpos in C-layout (shfl_xor partner), LDS transpose, frag stores.
// LDS 14 KB -> 4 blocks/CU.
// ---------------------------------------------------------------------------
__global__ __launch_bounds__(256, 4) void proj_kernel(
    const float* __restrict__ X, const __hip_bfloat16* __restrict__ Wfrag,
    const float* __restrict__ tabs,
    __hip_bfloat16* __restrict__ Qfrag, __hip_bfloat16* __restrict__ Kfrag,
    __hip_bfloat16* __restrict__ Vfrag)
{
    __shared__ __hip_bfloat16 smem[7168];   // 14336 B
    // main loop: lx = smem as [32][136]
    // epilogue: bufQ = smem[0..2303] [32][72], bufK = +2304 [32][72],
    //           bufV = +4608 [64][40] (transposed)

    int tid = threadIdx.x;
    int r0 = blockIdx.x * 32;               // global row base (b*2048 + n)
    int w = tid >> 6, lane = tid & 63, quad = lane >> 4, l15 = lane & 15;
    int rh = w & 1, nh = w >> 1;

    floatx4 acc[6];
#pragma unroll
    for (int t = 0; t < 6; t++) acc[t] = (floatx4){0.f, 0.f, 0.f, 0.f};

    for (int kb = 0; kb < 4; kb++) {
        // stage X tile 32x128 f32 -> bf16 LDS (4 float4 per thread, coalesced)
#pragma unroll
        for (int u = 0; u < 4; u++) {
            int f = u * 256 + tid;
            int row = f >> 5, c = f & 31;
            float4 v = *(const float4*)(X + (r0 + row) * 512 + kb * 128 + c * 4);
            ushort4 pk;
            pk.x = f2bf(v.x); pk.y = f2bf(v.y); pk.z = f2bf(v.z); pk.w = f2bf(v.w);
            *(ushort4*)&smem[row * 136 + c * 4] = pk;
        }
        __syncthreads();
#pragma unroll
        for (int ks = 0; ks < 4; ks++) {
            short8 a = *(const short8*)&smem[(rh * 16 + l15) * 136 + ks * 32 + quad * 8];
            int kkg = kb * 4 + ks;
#pragma unroll
            for (int t = 0; t < 6; t++) {
                int tile = nh * 6 + t;
                short8 bfr = *(const short8*)(Wfrag + ((tile * 16 + kkg) * 64 + lane) * 8);
                acc[t] = __builtin_amdgcn_mfma_f32_16x16x32_bf16(a, bfr, acc[t], 0, 0, 0);
            }
        }
        __syncthreads();
    }

    // ---- epilogue. C/D layout: col = l15, row = quad*4+rg ----
    __hip_bfloat16* bufQ = smem;
    __hip_bfloat16* bufK = smem + 2304;
    __hip_bfloat16* bufV = smem + 4608;
    int b = r0 >> 11, n0 = r0 & 2047;
    int rrow = rh * 16 + quad * 4;

#pragma unroll
    for (int tl = 0; tl < 6; tl++) {
        int t = nh * 6 + tl;
#pragma unroll
        for (int rg = 0; rg < 4; rg++) {
            int row = rrow + rg;            // 0..31 within block
            int n = n0 + row;
            float val = acc[tl][rg];
            float prt = __shfl_xor(val, 1, 64);  // lane^1 == col^1, same row
            if (t < 4) {                    // Q, xpos upscale
                int ch = t * 16 + l15, tt = ch >> 1;
                float co = tabs[n * 32 + tt];
                float si = tabs[65536 + n * 32 + tt];
                float o = (l15 & 1) ? (val * co + prt * si) : (val * co - prt * si);
                bufQ[row * 72 + ch] = __float2bfloat16(o);
            } else if (t < 8) {             // K, xpos downscale
                int ch = (t - 4) * 16 + l15, tt = ch >> 1;
                float co = tabs[131072 + n * 32 + tt];
                float si = tabs[196608 + n * 32 + tt];
                float o = (l15 & 1) ? (val * co + prt * si) : (val * co - prt * si);
                bufK[row * 72 + ch] = __float2bfloat16(o);
            } else {                        // V, transposed [ch][row]
                int ch = (t - 8) * 16 + l15;
                bufV[ch * 40 + row] = __float2bfloat16(val);
            }
        }
    }
    __syncthreads();

    // cooperative frag-order stores (each thread: 16 B ds_read + uint4 store)
    {
        int tile2 = tid >> 7, kk = (tid >> 6) & 1, ln = tid & 63;
        int q2 = ln >> 4, m15 = ln & 15;
        size_t qkbase = ((((size_t)b * 128 + (n0 >> 4) + tile2) * 2 + kk) * 64 + ln) * 8;
        uint4 vq = *(const uint4*)&bufQ[(tile2 * 16 + m15) * 72 + kk * 32 + q2 * 8];
        *(uint4*)(Qfrag + qkbase) = vq;
        uint4 vk = *(const uint4*)&bufK[(tile2 * 16 + m15) * 72 + kk * 32 + q2 * 8];
        *(uint4*)(Kfrag + qkbase) = vk;
        int t2 = tid >> 6;                  // 0..3
        uint4 vv = *(const uint4*)&bufV[(t2 * 16 + m15) * 40 + q2 * 8];
        *(uint4*)(Vfrag + ((((size_t)b * 64 + (n0 >> 5)) * 4 + t2) * 64 + ln) * 8) = vv;
    }
}

// ---------------------------------------------------------------------------
// Kernel 2: banded retention, barrier-free hot loop.
// 512 blocks = (b, 32 q-rows). Waves (qh, h): q-half, chunk-half.
// Each wave: full 16-tile QK for its chunks (kc0+h, kc0+h+2), decay,
// wave-private P LDS round-trip (in-wave DS ordering -> no barrier), PV with
// B-frags from L2 Vfrag. One barrier at the end to sum the two chunk halves.
// KV chunks qc-3..qc (gamma^768 ~ 2.6e-11 << threshold).
// ---------------------------------------------------------------------------
__global__ __launch_bounds__(256, 3) void attn_kernel(
    const __hip_bfloat16* __restrict__ Qfrag, const __hip_bfloat16* __restrict__ Kfrag,
    const __hip_bfloat16* __restrict__ Vfrag, float* __restrict__ out)
{
    __shared__ __hip_bfloat16 lp[4][16 * 264];   // 33792 B, per-wave private

    int tid = threadIdx.x;
    int b = blockIdx.x >> 6, qt = blockIdx.x & 63;
    int q0 = qt * 32, qc = q0 >> 8;
    int w = tid >> 6, lane = tid & 63, quad = lane >> 4, l15 = lane & 15;
    int qh = w >> 1, h = w & 1;
    int qt16 = (q0 >> 4) + qh;

    // Q A-frags for this wave's 16 rows (coalesced 1 KB loads)
    short8 qf[2];
#pragma unroll
    for (int kk = 0; kk < 2; kk++)
        qf[kk] = *(const short8*)(Qfrag + ((((size_t)b * 128 + qt16) * 2 + kk) * 64 + lane) * 8);

    __hip_bfloat16* P = &lp[w][0];               // [16][264]

    floatx4 o[4];
#pragma unroll
    for (int t = 0; t < 4; t++) o[t] = (floatx4){0.f, 0.f, 0.f, 0.f};

    int kc0 = (qc >= 3) ? (qc - 3) : 0;
    for (int kc = kc0 + h; kc <= qc; kc += 2) {
        // S = Q K^T : 16 kv-tiles, B-frags straight from L2 Kfrag
        floatx4 s[16];
#pragma unroll
        for (int t = 0; t < 16; t++) s[t] = (floatx4){0.f, 0.f, 0.f, 0.f};
#pragma unroll
        for (int t = 0; t < 16; t++) {
#pragma unroll
            for (int kk = 0; kk < 2; kk++) {
                short8 bfr = *(const short8*)(Kfrag +
                    ((((size_t)b * 128 + kc * 16 + t) * 2 + kk) * 64 + lane) * 8);
                s[t] = __builtin_amdgcn_mfma_f32_16x16x32_bf16(qf[kk], bfr, s[t], 0, 0, 0);
            }
        }

        // decay + P write (C-layout row=quad*4+rg, col=t*16+l15)
        int i0 = q0 + qh * 16 + quad * 4;
        int kbase = kc * 256;
#pragma unroll
        for (int t = 0; t < 16; t++) {
            int j = kbase + t * 16 + l15;
#pragma unroll
            for (int rg = 0; rg < 4; rg++) {
                int d = i0 + rg - j; d = (d < 0) ? -d : d;
                float p = s[t][rg] * exp2f(LOG2GAMMA * (float)d);
                P[(quad * 4 + rg) * 264 + t * 16 + l15] = __float2bfloat16(p);
            }
        }

        // PV: A from wave-private P (same-wave DS ordering), B from L2 Vfrag
#pragma unroll
        for (int ks = 0; ks < 8; ks++) {
            short8 a = *(const short8*)&P[l15 * 264 + ks * 32 + quad * 8];
#pragma unroll
            for (int t2 = 0; t2 < 4; t2++) {
                short8 bfr = *(const short8*)(Vfrag +
                    ((((size_t)b * 64 + kc * 8 + ks) * 4 + t2) * 64 + lane) * 8);
                o[t2] = __builtin_amdgcn_mfma_f32_16x16x32_bf16(a, bfr, o[t2], 0, 0, 0);
            }
        }
    }

    // combine chunk halves: h==1 stashes o (f32) in its P region, h==0 adds
    float* mine = (float*)&lp[w][0];
    float* part = (float*)&lp[w ^ 1][0];
    if (h == 1) {
#pragma unroll
        for (int t2 = 0; t2 < 4; t2++)
#pragma unroll
            for (int rg = 0; rg < 4; rg++)
                mine[(quad * 4 + rg) * 64 + t2 * 16 + l15] = o[t2][rg];
    }
    __syncthreads();
    if (h == 0) {
        int rbase = b * 2048 + q0 + qh * 16 + quad * 4;
#pragma unroll
        for (int t2 = 0; t2 < 4; t2++)
#pragma unroll
            for (int rg = 0; rg < 4; rg++)
                out[(size_t)(rbase + rg) * 64 + t2 * 16 + l15] =
                    o[t2][rg] + part[(quad * 4 + rg) * 64 + t2 * 16 + l15];
    }
}

// ---------------------------------------------------------------------------
extern "C" void kernel_launch(void* const* d_in, const int* in_sizes, int n_in,
                              void* d_out, int out_size, void* d_ws, size_t ws_size,
                              hipStream_t stream) {
    const float* X  = (const float*)d_in[0];
    const float* Wq = (const float*)d_in[1];
    const float* Wk = (const float*)d_in[2];
    const float* Wv = (const float*)d_in[3];
    float* out = (float*)d_out;

    char* ws = (char*)d_ws;
    __hip_bfloat16* Wfrag = (__hip_bfloat16*)(ws);            // 196608 B
    float*          tabs  = (float*)(ws + 196608);            // 1048576 B
    __hip_bfloat16* Qfrag = (__hip_bfloat16*)(ws + 1245184);  // 2097152 B
    __hip_bfloat16* Kfrag = (__hip_bfloat16*)(ws + 3342336);  // 2097152 B
    __hip_bfloat16* Vfrag = (__hip_bfloat16*)(ws + 5439488);  // 2097152 B

    prep_kernel<<<1408, 256, 0, stream>>>(Wq, Wk, Wv, Wfrag, tabs);
    proj_kernel<<<512, 256, 0, stream>>>(X, Wfrag, tabs, Qfrag, Kfrag, Vfrag);
    attn_kernel<<<512, 256, 0, stream>>>(Qfrag, Kfrag, Vfrag, out);
}